// Round 1
// baseline (5400.085 us; speedup 1.0000x reference)
//
#include <hip/hip_runtime.h>
#include <cstdint>
#include <cstddef>

#define NA 50000
#define NT 100000
#define FA 128
#define FT 64
#define HID 128
#define OUTF 64
#define HEADS 8
#define E1 500000
#define E2 250000

// ---- monotone float<->uint encoding so memset(0) == -inf for atomicMax ----
static __device__ __forceinline__ unsigned int enc_f(float f) {
  unsigned int u = __float_as_uint(f);
  return u ^ ((u & 0x80000000u) ? 0xFFFFFFFFu : 0x80000000u);
}
static __device__ __forceinline__ float dec_f(unsigned int u) {
  u ^= ((u & 0x80000000u) ? 0x80000000u : 0xFFFFFFFFu);
  return __uint_as_float(u);
}

// ---------------- tiled f32 GEMM: C[N,M] = A[N,K] @ W[K,M] + bias ---------
// MODE 0: store C.  MODE 1: score reduction: atomicAdd(sum tanh(C+bias)*q)
template<int MODE, bool RELU_A>
__global__ __launch_bounds__(256) void gemm_k(
    const float* __restrict__ A, const float* __restrict__ W,
    const float* __restrict__ bias, const float* __restrict__ qv,
    float* __restrict__ C, float* __restrict__ score,
    int N, int K, int M)
{
  __shared__ __align__(16) float As[16][68];
  __shared__ __align__(16) float Bs[16][68];
  __shared__ float red[4];
  int tid = threadIdx.x;
  int row0 = blockIdx.x * 64, col0 = blockIdx.y * 64;
  int tx = tid & 15, ty = tid >> 4;
  int ar = tid >> 2, ak = (tid & 3) << 2;   // A tile: 64 rows x 16 k
  int bk = tid >> 4, bj = (tid & 15) << 2;  // B tile: 16 k x 64 cols
  float acc[4][4] = {};
  int arow = row0 + ar;
  const float* Ap = A + (size_t)arow * K + ak;
  const float* Wp = W + (size_t)bk * M + col0 + bj;

  for (int k0 = 0; k0 < K; k0 += 16) {
    float4 av = make_float4(0.f, 0.f, 0.f, 0.f);
    if (arow < N) av = *reinterpret_cast<const float4*>(Ap + k0);
    if (RELU_A) {
      av.x = fmaxf(av.x, 0.f); av.y = fmaxf(av.y, 0.f);
      av.z = fmaxf(av.z, 0.f); av.w = fmaxf(av.w, 0.f);
    }
    float4 bv = *reinterpret_cast<const float4*>(Wp + (size_t)k0 * M);
    As[ak + 0][ar] = av.x; As[ak + 1][ar] = av.y;
    As[ak + 2][ar] = av.z; As[ak + 3][ar] = av.w;
    *reinterpret_cast<float4*>(&Bs[bk][bj]) = bv;
    __syncthreads();
#pragma unroll
    for (int kk = 0; kk < 16; ++kk) {
      float4 a4 = *reinterpret_cast<const float4*>(&As[kk][ty << 2]);
      float4 b4 = *reinterpret_cast<const float4*>(&Bs[kk][tx << 2]);
      float aa[4] = {a4.x, a4.y, a4.z, a4.w};
      float bb[4] = {b4.x, b4.y, b4.z, b4.w};
#pragma unroll
      for (int i = 0; i < 4; i++)
#pragma unroll
        for (int j = 0; j < 4; j++) acc[i][j] = fmaf(aa[i], bb[j], acc[i][j]);
    }
    __syncthreads();
  }

  if (MODE == 0) {
#pragma unroll
    for (int i = 0; i < 4; i++) {
      int r = row0 + (ty << 2) + i;
      if (r < N) {
        int c = col0 + (tx << 2);
        float4 st;
        st.x = acc[i][0] + bias[c + 0];
        st.y = acc[i][1] + bias[c + 1];
        st.z = acc[i][2] + bias[c + 2];
        st.w = acc[i][3] + bias[c + 3];
        *reinterpret_cast<float4*>(C + (size_t)r * M + c) = st;
      }
    }
  } else {
    float local = 0.f;
#pragma unroll
    for (int i = 0; i < 4; i++) {
      int r = row0 + (ty << 2) + i;
      if (r < N) {
#pragma unroll
        for (int j = 0; j < 4; j++) {
          int c = col0 + (tx << 2) + j;
          local += tanhf(acc[i][j] + bias[c]) * qv[c];
        }
      }
    }
#pragma unroll
    for (int o = 32; o > 0; o >>= 1) local += __shfl_xor(local, o);
    int wv = tid >> 6, ln = tid & 63;
    if (ln == 0) red[wv] = local;
    __syncthreads();
    if (tid == 0) atomicAdd(score, red[0] + red[1] + red[2] + red[3]);
  }
}

// --------- per-node attention logits: o_k[n,h] = dot(z[n,h,:], v_k[h,:]) ----
template<int D, int NV>
__global__ void node_alphas_k(const float* __restrict__ z, int N,
    const float* __restrict__ v0, const float* __restrict__ v1,
    const float* __restrict__ v2, const float* __restrict__ v3,
    float* __restrict__ o0, float* __restrict__ o1,
    float* __restrict__ o2, float* __restrict__ o3)
{
  int t = blockIdx.x * blockDim.x + threadIdx.x;
  if (t >= N * HEADS) return;
  int h = t & 7;
  const float* zp = z + (size_t)(t >> 3) * (HEADS * D) + h * D;
  float s0 = 0.f, s1 = 0.f, s2 = 0.f, s3 = 0.f;
#pragma unroll
  for (int i = 0; i < D; i++) {
    float zv = zp[i];
    s0 = fmaf(zv, v0[h * D + i], s0);
    if (NV > 1) s1 = fmaf(zv, v1[h * D + i], s1);
    if (NV > 2) s2 = fmaf(zv, v2[h * D + i], s2);
    if (NV > 3) s3 = fmaf(zv, v3[h * D + i], s3);
  }
  o0[t] = s0;
  if (NV > 1) o1[t] = s1;
  if (NV > 2) o2[t] = s2;
  if (NV > 3) o3[t] = s3;
}

static __device__ __forceinline__ void load8(const float* __restrict__ p, float* v) {
  float4 t0 = reinterpret_cast<const float4*>(p)[0];
  float4 t1 = reinterpret_cast<const float4*>(p)[1];
  v[0] = t0.x; v[1] = t0.y; v[2] = t0.z; v[3] = t0.w;
  v[4] = t1.x; v[5] = t1.y; v[6] = t1.z; v[7] = t1.w;
}

// ---- edge pass 1: leaky-relu(alpha) -> atomicMax into encoded max buffer ----
__global__ void edge_p1(const int* __restrict__ src, const int* __restrict__ dst, int E,
    const float* __restrict__ als, const float* __restrict__ ald,
    unsigned int* __restrict__ menc)
{
  int e = blockIdx.x * blockDim.x + threadIdx.x;
  if (e >= E) return;
  int s = src[e], d = dst[e];
  float a_s[8], a_d[8];
  load8(als + (size_t)s * 8, a_s);
  load8(ald + (size_t)d * 8, a_d);
#pragma unroll
  for (int h = 0; h < 8; h++) {
    float a = a_s[h] + a_d[h];
    a = a > 0.f ? a : 0.2f * a;
    atomicMax(&menc[(size_t)d * 8 + h], enc_f(a));
  }
}

// ---- edge pass 2: exp(alpha - m[dst]) -> atomicAdd denom ----
__global__ void edge_p2(const int* __restrict__ src, const int* __restrict__ dst, int E,
    const float* __restrict__ als, const float* __restrict__ ald,
    const unsigned int* __restrict__ menc, float* __restrict__ den)
{
  int e = blockIdx.x * blockDim.x + threadIdx.x;
  if (e >= E) return;
  int s = src[e], d = dst[e];
  float a_s[8], a_d[8];
  load8(als + (size_t)s * 8, a_s);
  load8(ald + (size_t)d * 8, a_d);
#pragma unroll
  for (int h = 0; h < 8; h++) {
    float a = a_s[h] + a_d[h];
    a = a > 0.f ? a : 0.2f * a;
    float m = dec_f(menc[(size_t)d * 8 + h]);
    atomicAdd(&den[(size_t)d * 8 + h], __expf(a - m));
  }
}

// ---- edge pass 3: weighted message aggregation (atomic scatter-add) ----
template<int F, int D>
__global__ void edge_p3_k(const int* __restrict__ src, const int* __restrict__ dst, int E,
    const float* __restrict__ als, const float* __restrict__ ald,
    const unsigned int* __restrict__ menc, const float* __restrict__ den,
    const float* __restrict__ zsrc, float* __restrict__ out)
{
  constexpr int TPE = F / 4;
  int t = blockIdx.x * blockDim.x + threadIdx.x;
  int e = t / TPE;
  if (e >= E) return;
  int c = t % TPE;
  int s = src[e], d = dst[e];
  int h = (c * 4) / D;
  float a = als[(size_t)s * 8 + h] + ald[(size_t)d * 8 + h];
  a = a > 0.f ? a : 0.2f * a;
  float ex = __expf(a - dec_f(menc[(size_t)d * 8 + h]));
  float w = ex / fmaxf(den[(size_t)d * 8 + h], 1e-16f);
  float4 v = reinterpret_cast<const float4*>(zsrc + (size_t)s * F)[c];
  float* op = out + (size_t)d * F + c * 4;
  atomicAdd(op + 0, v.x * w);
  atomicAdd(op + 1, v.y * w);
  atomicAdd(op + 2, v.z * w);
  atomicAdd(op + 3, v.w * w);
}

// ---- semantic softmax (K=2) combine + LayerNorm + ReLU, wave per node ----
template<int F>
__global__ __launch_bounds__(256) void combine_ln_k(
    const float* __restrict__ o0, const float* __restrict__ o1,
    const float* __restrict__ sc, float inv_n,
    const float* __restrict__ g, const float* __restrict__ b,
    float* __restrict__ outp, int N)
{
  int wv = threadIdx.x >> 6, lane = threadIdx.x & 63;
  int n = blockIdx.x * 4 + wv;
  if (n >= N) return;
  float s0 = sc[0] * inv_n, s1 = sc[1] * inv_n;
  float mx = fmaxf(s0, s1);
  float e0 = __expf(s0 - mx), e1 = __expf(s1 - mx);
  float w0 = e0 / (e0 + e1), w1 = e1 / (e0 + e1);
  constexpr int J = F / 64;
  float x[J];
#pragma unroll
  for (int j = 0; j < J; j++) {
    int idx = lane + 64 * j;
    x[j] = w0 * fmaxf(o0[(size_t)n * F + idx], 0.f)
         + w1 * fmaxf(o1[(size_t)n * F + idx], 0.f);
  }
  float sum = 0.f;
#pragma unroll
  for (int j = 0; j < J; j++) sum += x[j];
#pragma unroll
  for (int o = 32; o > 0; o >>= 1) sum += __shfl_xor(sum, o);
  float mu = sum / F;
  float vs = 0.f;
#pragma unroll
  for (int j = 0; j < J; j++) { float dd = x[j] - mu; vs = fmaf(dd, dd, vs); }
#pragma unroll
  for (int o = 32; o > 0; o >>= 1) vs += __shfl_xor(vs, o);
  float rstd = rsqrtf(vs / F + 1e-5f);
#pragma unroll
  for (int j = 0; j < J; j++) {
    int idx = lane + 64 * j;
    float y = (x[j] - mu) * rstd * g[idx] + b[idx];
    outp[(size_t)n * F + idx] = fmaxf(y, 0.f);
  }
}

// ---- final linear [N,64] @ [64,2] + b, wave per node ----
__global__ __launch_bounds__(256) void final_lin_k(const float* __restrict__ xa,
    const float* __restrict__ W, const float* __restrict__ bias,
    float* __restrict__ outp, int N)
{
  int wv = threadIdx.x >> 6, lane = threadIdx.x & 63;
  int n = blockIdx.x * 4 + wv;
  if (n >= N) return;
  float v = xa[(size_t)n * 64 + lane];
  float p0 = v * W[lane * 2 + 0];
  float p1 = v * W[lane * 2 + 1];
#pragma unroll
  for (int o = 32; o > 0; o >>= 1) { p0 += __shfl_xor(p0, o); p1 += __shfl_xor(p1, o); }
  if (lane == 0) {
    outp[(size_t)n * 2 + 0] = p0 + bias[0];
    outp[(size_t)n * 2 + 1] = p1 + bias[1];
  }
}

extern "C" void kernel_launch(void* const* d_in, const int* in_sizes, int n_in,
                              void* d_out, int out_size, void* d_ws, size_t ws_size,
                              hipStream_t stream)
{
  (void)in_sizes; (void)n_in; (void)out_size;
  const float* x_a   = (const float*)d_in[0];
  const float* x_t   = (const float*)d_in[1];
  const int* eat_s = (const int*)d_in[2];
  const int* eat_d = (const int*)d_in[3];
  const int* eta_s = (const int*)d_in[4];
  const int* eta_d = (const int*)d_in[5];
  const int* eaa_s = (const int*)d_in[6];
  const int* eaa_d = (const int*)d_in[7];
  const int* ett_s = (const int*)d_in[8];
  const int* ett_d = (const int*)d_in[9];
  const float* W_a1 = (const float*)d_in[10]; const float* b_a1 = (const float*)d_in[11];
  const float* W_t1 = (const float*)d_in[12]; const float* b_t1 = (const float*)d_in[13];
  const float* as_at1 = (const float*)d_in[14]; const float* ad_at1 = (const float*)d_in[15];
  const float* as_ta1 = (const float*)d_in[16]; const float* ad_ta1 = (const float*)d_in[17];
  const float* as_aa1 = (const float*)d_in[18]; const float* ad_aa1 = (const float*)d_in[19];
  const float* as_tt1 = (const float*)d_in[20]; const float* ad_tt1 = (const float*)d_in[21];
  const float* k1_W = (const float*)d_in[22]; const float* k1_b = (const float*)d_in[23];
  const float* q1   = (const float*)d_in[24];
  const float* W_a2 = (const float*)d_in[25]; const float* b_a2 = (const float*)d_in[26];
  const float* W_t2 = (const float*)d_in[27]; const float* b_t2 = (const float*)d_in[28];
  const float* as_ta2 = (const float*)d_in[31]; const float* ad_ta2 = (const float*)d_in[32];
  const float* as_aa2 = (const float*)d_in[33]; const float* ad_aa2 = (const float*)d_in[34];
  const float* k2_W = (const float*)d_in[37]; const float* k2_b = (const float*)d_in[38];
  const float* q2   = (const float*)d_in[39];
  const float* ln1_g = (const float*)d_in[40]; const float* ln1_b = (const float*)d_in[41];
  const float* ln2_g = (const float*)d_in[42]; const float* ln2_b = (const float*)d_in[43];
  const float* lin_W = (const float*)d_in[44]; const float* lin_b = (const float*)d_in[45];

  char* ws = (char*)d_ws;
  size_t off = 0;
  auto alloc = [&](size_t bytes) {
    size_t o = off; off += (bytes + 255) & ~(size_t)255; return o;
  };
  size_t ZA1 = alloc((size_t)NA * HID * 4);     // layer2: za2 [NA,64] aliases
  size_t ZT1 = alloc((size_t)NT * HID * 4);     // layer2: zt2 [NT,64] aliases
  size_t OTA = alloc((size_t)NA * HID * 4);     // -> xa1 in-place
  size_t OAA = alloc((size_t)NA * HID * 4);     // layer2: o_ta2|o_aa2 aliases
  size_t OAT = alloc((size_t)NT * HID * 4);     // -> xt1 in-place
  size_t OTT = alloc((size_t)NT * HID * 4);
  size_t A_AS_AT = alloc((size_t)NA * 8 * 4);
  size_t A_AD_TA = alloc((size_t)NA * 8 * 4);
  size_t A_AS_AA = alloc((size_t)NA * 8 * 4);
  size_t A_AD_AA = alloc((size_t)NA * 8 * 4);
  size_t A_T_D_AT = alloc((size_t)NT * 8 * 4);
  size_t A_T_S_TA = alloc((size_t)NT * 8 * 4);
  size_t A_T_S_TT = alloc((size_t)NT * 8 * 4);
  size_t A_T_D_TT = alloc((size_t)NT * 8 * 4);
  size_t MB  = alloc((size_t)NT * 8 * 4);       // shared max buffer (encoded)
  size_t DB  = alloc((size_t)NT * 8 * 4);       // shared denom buffer
  size_t SC  = alloc(256);                      // 6 score accumulators
  if (off > ws_size) return;                    // fail visibly (output stays poisoned)

  float* za1 = (float*)(ws + ZA1);
  float* zt1 = (float*)(ws + ZT1);
  float* ota = (float*)(ws + OTA);
  float* oaa = (float*)(ws + OAA);
  float* oat = (float*)(ws + OAT);
  float* ott = (float*)(ws + OTT);
  float* aASAT = (float*)(ws + A_AS_AT);
  float* aADTA = (float*)(ws + A_AD_TA);
  float* aASAA = (float*)(ws + A_AS_AA);
  float* aADAA = (float*)(ws + A_AD_AA);
  float* aTDAT = (float*)(ws + A_T_D_AT);
  float* aTSTA = (float*)(ws + A_T_S_TA);
  float* aTSTT = (float*)(ws + A_T_S_TT);
  float* aTDTT = (float*)(ws + A_T_D_TT);
  unsigned int* menc = (unsigned int*)(ws + MB);
  float* den = (float*)(ws + DB);
  float* scp = (float*)(ws + SC);
  // layer-2 aliases
  float* za2  = za1;                                  // [NA,64]
  float* zt2  = zt1;                                  // [NT,64]
  float* ota2 = oaa;                                  // [NA,64]
  float* oaa2 = (float*)(ws + OAA + (size_t)NA * OUTF * 4);  // [NA,64]

  const int GA  = (NA + 63) / 64, GT = (NT + 63) / 64;
  const int B1  = (E1 + 255) / 256, B2 = (E2 + 255) / 256;
  const int P3A1 = ((E1 * 32) + 255) / 256, P3B1 = ((E2 * 32) + 255) / 256;
  const int P3A2 = ((E1 * 16) + 255) / 256, P3B2 = ((E2 * 16) + 255) / 256;
  const int NBA = (NA * 8 + 255) / 256, NBT = (NT * 8 + 255) / 256;

  hipMemsetAsync(ws + SC, 0, 256, stream);

  // ============ Layer 1 ============
  gemm_k<0,false><<<dim3(GA,2),256,0,stream>>>(x_a, W_a1, b_a1, nullptr, za1, nullptr, NA, FA, HID);
  gemm_k<0,false><<<dim3(GT,2),256,0,stream>>>(x_t, W_t1, b_t1, nullptr, zt1, nullptr, NT, FT, HID);
  node_alphas_k<16,4><<<NBA,256,0,stream>>>(za1, NA, as_at1, ad_ta1, as_aa1, ad_aa1,
                                            aASAT, aADTA, aASAA, aADAA);
  node_alphas_k<16,4><<<NBT,256,0,stream>>>(zt1, NT, ad_at1, as_ta1, as_tt1, ad_tt1,
                                            aTDAT, aTSTA, aTSTT, aTDTT);
  // --- a->t (dst NT) ---
  hipMemsetAsync(ws + MB, 0, (size_t)NT*8*4, stream);
  hipMemsetAsync(ws + DB, 0, (size_t)NT*8*4, stream);
  hipMemsetAsync(ws + OAT, 0, (size_t)NT*HID*4, stream);
  edge_p1<<<B1,256,0,stream>>>(eat_s, eat_d, E1, aASAT, aTDAT, menc);
  edge_p2<<<B1,256,0,stream>>>(eat_s, eat_d, E1, aASAT, aTDAT, menc, den);
  edge_p3_k<128,16><<<P3A1,256,0,stream>>>(eat_s, eat_d, E1, aASAT, aTDAT, menc, den, za1, oat);
  // --- t->a (dst NA) ---
  hipMemsetAsync(ws + MB, 0, (size_t)NA*8*4, stream);
  hipMemsetAsync(ws + DB, 0, (size_t)NA*8*4, stream);
  hipMemsetAsync(ws + OTA, 0, (size_t)NA*HID*4, stream);
  edge_p1<<<B1,256,0,stream>>>(eta_s, eta_d, E1, aTSTA, aADTA, menc);
  edge_p2<<<B1,256,0,stream>>>(eta_s, eta_d, E1, aTSTA, aADTA, menc, den);
  edge_p3_k<128,16><<<P3A1,256,0,stream>>>(eta_s, eta_d, E1, aTSTA, aADTA, menc, den, zt1, ota);
  // --- a->a ---
  hipMemsetAsync(ws + MB, 0, (size_t)NA*8*4, stream);
  hipMemsetAsync(ws + DB, 0, (size_t)NA*8*4, stream);
  hipMemsetAsync(ws + OAA, 0, (size_t)NA*HID*4, stream);
  edge_p1<<<B2,256,0,stream>>>(eaa_s, eaa_d, E2, aASAA, aADAA, menc);
  edge_p2<<<B2,256,0,stream>>>(eaa_s, eaa_d, E2, aASAA, aADAA, menc, den);
  edge_p3_k<128,16><<<P3B1,256,0,stream>>>(eaa_s, eaa_d, E2, aASAA, aADAA, menc, den, za1, oaa);
  // --- t->t ---
  hipMemsetAsync(ws + MB, 0, (size_t)NT*8*4, stream);
  hipMemsetAsync(ws + DB, 0, (size_t)NT*8*4, stream);
  hipMemsetAsync(ws + OTT, 0, (size_t)NT*HID*4, stream);
  edge_p1<<<B2,256,0,stream>>>(ett_s, ett_d, E2, aTSTT, aTDTT, menc);
  edge_p2<<<B2,256,0,stream>>>(ett_s, ett_d, E2, aTSTT, aTDTT, menc, den);
  edge_p3_k<128,16><<<P3B1,256,0,stream>>>(ett_s, ett_d, E2, aTSTT, aTDTT, menc, den, zt1, ott);
  // --- semantic scores + combine + LN + relu ---
  gemm_k<1,true><<<dim3(GA,2),256,0,stream>>>(ota, k1_W, k1_b, q1, nullptr, scp+0, NA, HID, HID);
  gemm_k<1,true><<<dim3(GA,2),256,0,stream>>>(oaa, k1_W, k1_b, q1, nullptr, scp+1, NA, HID, HID);
  gemm_k<1,true><<<dim3(GT,2),256,0,stream>>>(oat, k1_W, k1_b, q1, nullptr, scp+2, NT, HID, HID);
  gemm_k<1,true><<<dim3(GT,2),256,0,stream>>>(ott, k1_W, k1_b, q1, nullptr, scp+3, NT, HID, HID);
  combine_ln_k<128><<<(NA+3)/4,256,0,stream>>>(ota, oaa, scp+0, 1.f/NA, ln1_g, ln1_b, ota, NA); // xa1
  combine_ln_k<128><<<(NT+3)/4,256,0,stream>>>(oat, ott, scp+2, 1.f/NT, ln1_g, ln1_b, oat, NT); // xt1

  // ============ Layer 2 (only the address path feeds the output) ============
  gemm_k<0,false><<<dim3(GA,1),256,0,stream>>>(ota, W_a2, b_a2, nullptr, za2, nullptr, NA, HID, OUTF);
  gemm_k<0,false><<<dim3(GT,1),256,0,stream>>>(oat, W_t2, b_t2, nullptr, zt2, nullptr, NT, HID, OUTF);
  node_alphas_k<8,3><<<NBA,256,0,stream>>>(za2, NA, ad_ta2, as_aa2, ad_aa2, ad_aa2,
                                           aADTA, aASAA, aADAA, aADAA);
  node_alphas_k<8,1><<<NBT,256,0,stream>>>(zt2, NT, as_ta2, as_ta2, as_ta2, as_ta2,
                                           aTSTA, aTSTA, aTSTA, aTSTA);
  // --- t->a ---
  hipMemsetAsync(ws + MB, 0, (size_t)NA*8*4, stream);
  hipMemsetAsync(ws + DB, 0, (size_t)NA*8*4, stream);
  hipMemsetAsync(ws + OAA, 0, (size_t)2*NA*OUTF*4, stream);  // zero o_ta2 and o_aa2
  edge_p1<<<B1,256,0,stream>>>(eta_s, eta_d, E1, aTSTA, aADTA, menc);
  edge_p2<<<B1,256,0,stream>>>(eta_s, eta_d, E1, aTSTA, aADTA, menc, den);
  edge_p3_k<64,8><<<P3A2,256,0,stream>>>(eta_s, eta_d, E1, aTSTA, aADTA, menc, den, zt2, ota2);
  // --- a->a ---
  hipMemsetAsync(ws + MB, 0, (size_t)NA*8*4, stream);
  hipMemsetAsync(ws + DB, 0, (size_t)NA*8*4, stream);
  edge_p1<<<B2,256,0,stream>>>(eaa_s, eaa_d, E2, aASAA, aADAA, menc);
  edge_p2<<<B2,256,0,stream>>>(eaa_s, eaa_d, E2, aASAA, aADAA, menc, den);
  edge_p3_k<64,8><<<P3B2,256,0,stream>>>(eaa_s, eaa_d, E2, aASAA, aADAA, menc, den, za2, oaa2);
  // --- scores + combine + LN + relu ---
  gemm_k<1,true><<<dim3(GA,1),256,0,stream>>>(ota2, k2_W, k2_b, q2, nullptr, scp+4, NA, OUTF, OUTF);
  gemm_k<1,true><<<dim3(GA,1),256,0,stream>>>(oaa2, k2_W, k2_b, q2, nullptr, scp+5, NA, OUTF, OUTF);
  combine_ln_k<64><<<(NA+3)/4,256,0,stream>>>(ota2, oaa2, scp+4, 1.f/NA, ln2_g, ln2_b, ota2, NA); // xa2

  final_lin_k<<<(NA+3)/4,256,0,stream>>>(ota2, lin_W, lin_b, (float*)d_out, NA);
}

// Round 2
// 1069.111 us; speedup vs baseline: 5.0510x; 5.0510x over previous
//
#include <hip/hip_runtime.h>
#include <cstdint>
#include <cstddef>

#define NA 50000
#define NT 100000
#define FA 128
#define FT 64
#define HID 128
#define OUTF 64
#define HEADS 8
#define E1 500000
#define E2 250000

// ---------------- tiled f32 GEMM: C[N,M] = A[N,K] @ W[K,M] + bias ---------
// MODE 0: store C.  MODE 1: score reduction: atomicAdd(sum tanh(C+bias)*q)
template<int MODE>
__global__ __launch_bounds__(256) void gemm_k(
    const float* __restrict__ A, const float* __restrict__ W,
    const float* __restrict__ bias, const float* __restrict__ qv,
    float* __restrict__ C, float* __restrict__ score,
    int N, int K, int M)
{
  __shared__ __align__(16) float As[16][68];
  __shared__ __align__(16) float Bs[16][68];
  __shared__ float red[4];
  int tid = threadIdx.x;
  int row0 = blockIdx.x * 64, col0 = blockIdx.y * 64;
  int tx = tid & 15, ty = tid >> 4;
  int ar = tid >> 2, ak = (tid & 3) << 2;   // A tile: 64 rows x 16 k
  int bk = tid >> 4, bj = (tid & 15) << 2;  // B tile: 16 k x 64 cols
  float acc[4][4] = {};
  int arow = row0 + ar;
  const float* Ap = A + (size_t)arow * K + ak;
  const float* Wp = W + (size_t)bk * M + col0 + bj;

  for (int k0 = 0; k0 < K; k0 += 16) {
    float4 av = make_float4(0.f, 0.f, 0.f, 0.f);
    if (arow < N) av = *reinterpret_cast<const float4*>(Ap + k0);
    float4 bv = *reinterpret_cast<const float4*>(Wp + (size_t)k0 * M);
    As[ak + 0][ar] = av.x; As[ak + 1][ar] = av.y;
    As[ak + 2][ar] = av.z; As[ak + 3][ar] = av.w;
    *reinterpret_cast<float4*>(&Bs[bk][bj]) = bv;
    __syncthreads();
#pragma unroll
    for (int kk = 0; kk < 16; ++kk) {
      float4 a4 = *reinterpret_cast<const float4*>(&As[kk][ty << 2]);
      float4 b4 = *reinterpret_cast<const float4*>(&Bs[kk][tx << 2]);
      float aa[4] = {a4.x, a4.y, a4.z, a4.w};
      float bb[4] = {b4.x, b4.y, b4.z, b4.w};
#pragma unroll
      for (int i = 0; i < 4; i++)
#pragma unroll
        for (int j = 0; j < 4; j++) acc[i][j] = fmaf(aa[i], bb[j], acc[i][j]);
    }
    __syncthreads();
  }

  if (MODE == 0) {
#pragma unroll
    for (int i = 0; i < 4; i++) {
      int r = row0 + (ty << 2) + i;
      if (r < N) {
        int c = col0 + (tx << 2);
        float4 st;
        st.x = acc[i][0] + bias[c + 0];
        st.y = acc[i][1] + bias[c + 1];
        st.z = acc[i][2] + bias[c + 2];
        st.w = acc[i][3] + bias[c + 3];
        *reinterpret_cast<float4*>(C + (size_t)r * M + c) = st;
      }
    }
  } else {
    float local = 0.f;
#pragma unroll
    for (int i = 0; i < 4; i++) {
      int r = row0 + (ty << 2) + i;
      if (r < N) {
#pragma unroll
        for (int j = 0; j < 4; j++) {
          int c = col0 + (tx << 2) + j;
          local += tanhf(acc[i][j] + bias[c]) * qv[c];
        }
      }
    }
#pragma unroll
    for (int o = 32; o > 0; o >>= 1) local += __shfl_xor(local, o);
    int wv = tid >> 6, ln = tid & 63;
    if (ln == 0) red[wv] = local;
    __syncthreads();
    if (tid == 0) atomicAdd(score, red[0] + red[1] + red[2] + red[3]);
  }
}

// --------- per-node attention logits: o_k[n,h] = dot(z[n,h,:], v_k[h,:]) ----
template<int D, int NV>
__global__ void node_alphas_k(const float* __restrict__ z, int N,
    const float* __restrict__ v0, const float* __restrict__ v1,
    const float* __restrict__ v2, const float* __restrict__ v3,
    float* __restrict__ o0, float* __restrict__ o1,
    float* __restrict__ o2, float* __restrict__ o3)
{
  int t = blockIdx.x * blockDim.x + threadIdx.x;
  if (t >= N * HEADS) return;
  int h = t & 7;
  const float* zp = z + (size_t)(t >> 3) * (HEADS * D) + h * D;
  float s0 = 0.f, s1 = 0.f, s2 = 0.f, s3 = 0.f;
#pragma unroll
  for (int i = 0; i < D; i++) {
    float zv = zp[i];
    s0 = fmaf(zv, v0[h * D + i], s0);
    if (NV > 1) s1 = fmaf(zv, v1[h * D + i], s1);
    if (NV > 2) s2 = fmaf(zv, v2[h * D + i], s2);
    if (NV > 3) s3 = fmaf(zv, v3[h * D + i], s3);
  }
  o0[t] = s0;
  if (NV > 1) o1[t] = s1;
  if (NV > 2) o2[t] = s2;
  if (NV > 3) o3[t] = s3;
}

// =================== CSR build (counting sort by dst) ======================
__global__ void csr_hist(const int* __restrict__ dst, int E, int* __restrict__ cnt)
{
  int e = blockIdx.x * blockDim.x + threadIdx.x;
  if (e < E) atomicAdd(&cnt[dst[e]], 1);
}

// per-block scan: 256 threads x 8 elems = 2048/block; writes inclusive scan
// of in[i] to rp1[i] (caller passes rp+1), block totals to bsum.
__global__ __launch_bounds__(256) void scan_blk(const int* __restrict__ in,
    int* __restrict__ rp1, int* __restrict__ bsum, int n)
{
  __shared__ int sh[256];
  int base = blockIdx.x * 2048;
  int t = threadIdx.x;
  int v[8]; int s = 0;
#pragma unroll
  for (int k = 0; k < 8; k++) {
    int i = base + t * 8 + k;
    v[k] = (i < n) ? in[i] : 0; s += v[k];
  }
  sh[t] = s; __syncthreads();
  for (int o = 1; o < 256; o <<= 1) {
    int x = (t >= o) ? sh[t - o] : 0;
    __syncthreads(); sh[t] += x; __syncthreads();
  }
  int run = (t == 0) ? 0 : sh[t - 1];
  if (t == 255 && bsum) bsum[blockIdx.x] = sh[255];
#pragma unroll
  for (int k = 0; k < 8; k++) {
    int i = base + t * 8 + k;
    run += v[k];
    if (i < n) rp1[i] = run;
  }
}

// exclusive scan of block sums in-place; nb <= 64, single wave
__global__ void scan_bsum(int* __restrict__ bsum, int nb)
{
  int t = threadIdx.x;
  int v = (t < nb) ? bsum[t] : 0;
  int orig = v;
#pragma unroll
  for (int o = 1; o < 64; o <<= 1) {
    int u = __shfl_up(v, o);
    if (t >= o) v += u;
  }
  if (t < nb) bsum[t] = v - orig;
}

// add block offsets; also writes rp[0] = 0
__global__ void scan_add(int* __restrict__ rp, const int* __restrict__ bsum, int n)
{
  int i = blockIdx.x * blockDim.x + threadIdx.x;
  if (i == 0) rp[0] = 0;
  if (i < n) rp[i + 1] += bsum[i >> 11];
}

__global__ void csr_scatter(const int* __restrict__ src, const int* __restrict__ dst,
    int E, int* __restrict__ cursor, int* __restrict__ ssrc)
{
  int e = blockIdx.x * blockDim.x + threadIdx.x;
  if (e < E) {
    int d = dst[e];
    int p = atomicAdd(&cursor[d], 1);
    ssrc[p] = src[e];
  }
}

// =============== atomic-free GAT aggregation: one wave per dst node ========
// lane = h*8 + j ; softmax phase: edge j+8k, head h ; accumulate phase:
// feature f = lane*(F/64), head f/(F/16) == lane>>3 (same h). ReLU fused.
template<int F>
__global__ __launch_bounds__(256) void agg_k(const int* __restrict__ rp,
    const int* __restrict__ ssrc,
    const float* __restrict__ als, const float* __restrict__ ald,
    const float* __restrict__ z, float* __restrict__ out, int Nd)
{
  int wv = threadIdx.x >> 6, lane = threadIdx.x & 63;
  int n = blockIdx.x * 4 + wv;
  if (n >= Nd) return;
  int start = rp[n], end = rp[n + 1];
  int h = lane >> 3, j = lane & 7;
  float ad_h = ald[(size_t)n * 8 + h];

  float m = -1e30f;
  for (int e0 = start; e0 < end; e0 += 8) {
    int e = e0 + j;
    float a = -1e30f;
    if (e < end) {
      int s = ssrc[e];
      a = als[(size_t)s * 8 + h] + ad_h;
      a = a > 0.f ? a : 0.2f * a;
    }
    m = fmaxf(m, a);
  }
  m = fmaxf(m, __shfl_xor(m, 1));
  m = fmaxf(m, __shfl_xor(m, 2));
  m = fmaxf(m, __shfl_xor(m, 4));

  float den = 0.f;
  for (int e0 = start; e0 < end; e0 += 8) {
    int e = e0 + j;
    if (e < end) {
      int s = ssrc[e];
      float a = als[(size_t)s * 8 + h] + ad_h;
      a = a > 0.f ? a : 0.2f * a;
      den += __expf(a - m);
    }
  }
  den += __shfl_xor(den, 1);
  den += __shfl_xor(den, 2);
  den += __shfl_xor(den, 4);
  float inv = 1.f / fmaxf(den, 1e-16f);

  if (F == 128) {
    float accx = 0.f, accy = 0.f;
    for (int e = start; e < end; e++) {
      int s = ssrc[e];
      float a = als[(size_t)s * 8 + h] + ad_h;
      a = a > 0.f ? a : 0.2f * a;
      float w = __expf(a - m) * inv;
      float2 zv = *reinterpret_cast<const float2*>(z + (size_t)s * 128 + lane * 2);
      accx = fmaf(w, zv.x, accx);
      accy = fmaf(w, zv.y, accy);
    }
    float2 st; st.x = fmaxf(accx, 0.f); st.y = fmaxf(accy, 0.f);
    *reinterpret_cast<float2*>(out + (size_t)n * 128 + lane * 2) = st;
  } else {
    float acc = 0.f;
    for (int e = start; e < end; e++) {
      int s = ssrc[e];
      float a = als[(size_t)s * 8 + h] + ad_h;
      a = a > 0.f ? a : 0.2f * a;
      float w = __expf(a - m) * inv;
      acc = fmaf(w, z[(size_t)s * 64 + lane], acc);
    }
    out[(size_t)n * 64 + lane] = fmaxf(acc, 0.f);
  }
}

// ---- semantic softmax (K=2) combine + LayerNorm + ReLU, wave per node ----
template<int F>
__global__ __launch_bounds__(256) void combine_ln_k(
    const float* __restrict__ o0, const float* __restrict__ o1,
    const float* __restrict__ sc, float inv_n,
    const float* __restrict__ g, const float* __restrict__ b,
    float* __restrict__ outp, int N)
{
  int wv = threadIdx.x >> 6, lane = threadIdx.x & 63;
  int n = blockIdx.x * 4 + wv;
  if (n >= N) return;
  float s0 = sc[0] * inv_n, s1 = sc[1] * inv_n;
  float mx = fmaxf(s0, s1);
  float e0 = __expf(s0 - mx), e1 = __expf(s1 - mx);
  float w0 = e0 / (e0 + e1), w1 = e1 / (e0 + e1);
  constexpr int J = F / 64;
  float x[J];
#pragma unroll
  for (int j = 0; j < J; j++) {
    int idx = lane + 64 * j;
    x[j] = w0 * o0[(size_t)n * F + idx] + w1 * o1[(size_t)n * F + idx];
  }
  float sum = 0.f;
#pragma unroll
  for (int j = 0; j < J; j++) sum += x[j];
#pragma unroll
  for (int o = 32; o > 0; o >>= 1) sum += __shfl_xor(sum, o);
  float mu = sum / F;
  float vs = 0.f;
#pragma unroll
  for (int j = 0; j < J; j++) { float dd = x[j] - mu; vs = fmaf(dd, dd, vs); }
#pragma unroll
  for (int o = 32; o > 0; o >>= 1) vs += __shfl_xor(vs, o);
  float rstd = rsqrtf(vs / F + 1e-5f);
#pragma unroll
  for (int j = 0; j < J; j++) {
    int idx = lane + 64 * j;
    float y = (x[j] - mu) * rstd * g[idx] + b[idx];
    outp[(size_t)n * F + idx] = fmaxf(y, 0.f);
  }
}

// ---- final linear [N,64] @ [64,2] + b, wave per node ----
__global__ __launch_bounds__(256) void final_lin_k(const float* __restrict__ xa,
    const float* __restrict__ W, const float* __restrict__ bias,
    float* __restrict__ outp, int N)
{
  int wv = threadIdx.x >> 6, lane = threadIdx.x & 63;
  int n = blockIdx.x * 4 + wv;
  if (n >= N) return;
  float v = xa[(size_t)n * 64 + lane];
  float p0 = v * W[lane * 2 + 0];
  float p1 = v * W[lane * 2 + 1];
#pragma unroll
  for (int o = 32; o > 0; o >>= 1) { p0 += __shfl_xor(p0, o); p1 += __shfl_xor(p1, o); }
  if (lane == 0) {
    outp[(size_t)n * 2 + 0] = p0 + bias[0];
    outp[(size_t)n * 2 + 1] = p1 + bias[1];
  }
}

extern "C" void kernel_launch(void* const* d_in, const int* in_sizes, int n_in,
                              void* d_out, int out_size, void* d_ws, size_t ws_size,
                              hipStream_t stream)
{
  (void)in_sizes; (void)n_in; (void)out_size;
  const float* x_a   = (const float*)d_in[0];
  const float* x_t   = (const float*)d_in[1];
  const int* eat_s = (const int*)d_in[2];
  const int* eat_d = (const int*)d_in[3];
  const int* eta_s = (const int*)d_in[4];
  const int* eta_d = (const int*)d_in[5];
  const int* eaa_s = (const int*)d_in[6];
  const int* eaa_d = (const int*)d_in[7];
  const int* ett_s = (const int*)d_in[8];
  const int* ett_d = (const int*)d_in[9];
  const float* W_a1 = (const float*)d_in[10]; const float* b_a1 = (const float*)d_in[11];
  const float* W_t1 = (const float*)d_in[12]; const float* b_t1 = (const float*)d_in[13];
  const float* as_at1 = (const float*)d_in[14]; const float* ad_at1 = (const float*)d_in[15];
  const float* as_ta1 = (const float*)d_in[16]; const float* ad_ta1 = (const float*)d_in[17];
  const float* as_aa1 = (const float*)d_in[18]; const float* ad_aa1 = (const float*)d_in[19];
  const float* as_tt1 = (const float*)d_in[20]; const float* ad_tt1 = (const float*)d_in[21];
  const float* k1_W = (const float*)d_in[22]; const float* k1_b = (const float*)d_in[23];
  const float* q1   = (const float*)d_in[24];
  const float* W_a2 = (const float*)d_in[25]; const float* b_a2 = (const float*)d_in[26];
  const float* W_t2 = (const float*)d_in[27]; const float* b_t2 = (const float*)d_in[28];
  const float* as_ta2 = (const float*)d_in[31]; const float* ad_ta2 = (const float*)d_in[32];
  const float* as_aa2 = (const float*)d_in[33]; const float* ad_aa2 = (const float*)d_in[34];
  const float* k2_W = (const float*)d_in[37]; const float* k2_b = (const float*)d_in[38];
  const float* q2   = (const float*)d_in[39];
  const float* ln1_g = (const float*)d_in[40]; const float* ln1_b = (const float*)d_in[41];
  const float* ln2_g = (const float*)d_in[42]; const float* ln2_b = (const float*)d_in[43];
  const float* lin_W = (const float*)d_in[44]; const float* lin_b = (const float*)d_in[45];

  char* ws = (char*)d_ws;
  size_t off = 0;
  auto alloc = [&](size_t bytes) {
    size_t o = off; off += (bytes + 255) & ~(size_t)255; return o;
  };
  size_t ZA1 = alloc((size_t)NA * HID * 4);     // layer2: za2 [NA,64] aliases
  size_t ZT1 = alloc((size_t)NT * HID * 4);     // layer2: zt2 [NT,64] aliases
  size_t OTA = alloc((size_t)NA * HID * 4);     // -> xa1 in-place
  size_t OAA = alloc((size_t)NA * HID * 4);     // layer2: o_ta2|o_aa2 aliases
  size_t OAT = alloc((size_t)NT * HID * 4);     // -> xt1 in-place
  size_t OTT = alloc((size_t)NT * HID * 4);
  size_t A_AS_AT = alloc((size_t)NA * 8 * 4);
  size_t A_AD_TA = alloc((size_t)NA * 8 * 4);
  size_t A_AS_AA = alloc((size_t)NA * 8 * 4);
  size_t A_AD_AA = alloc((size_t)NA * 8 * 4);
  size_t A_T_D_AT = alloc((size_t)NT * 8 * 4);
  size_t A_T_S_TA = alloc((size_t)NT * 8 * 4);
  size_t A_T_S_TT = alloc((size_t)NT * 8 * 4);
  size_t A_T_D_TT = alloc((size_t)NT * 8 * 4);
  // CSR structures
  size_t RP_AT = alloc((size_t)(NT + 1) * 4);
  size_t SS_AT = alloc((size_t)E1 * 4);
  size_t RP_TA = alloc((size_t)(NA + 1) * 4);
  size_t SS_TA = alloc((size_t)E1 * 4);
  size_t RP_AA = alloc((size_t)(NA + 1) * 4);
  size_t SS_AA = alloc((size_t)E2 * 4);
  size_t RP_TT = alloc((size_t)(NT + 1) * 4);
  size_t SS_TT = alloc((size_t)E2 * 4);
  size_t CNT = alloc((size_t)NT * 4);           // shared hist/cursor scratch
  size_t BSM = alloc(64 * 4);
  size_t SC  = alloc(256);                      // 6 score accumulators
  if (off > ws_size) return;                    // fail visibly (output stays poisoned)

  float* za1 = (float*)(ws + ZA1);
  float* zt1 = (float*)(ws + ZT1);
  float* ota = (float*)(ws + OTA);
  float* oaa = (float*)(ws + OAA);
  float* oat = (float*)(ws + OAT);
  float* ott = (float*)(ws + OTT);
  float* aASAT = (float*)(ws + A_AS_AT);
  float* aADTA = (float*)(ws + A_AD_TA);
  float* aASAA = (float*)(ws + A_AS_AA);
  float* aADAA = (float*)(ws + A_AD_AA);
  float* aTDAT = (float*)(ws + A_T_D_AT);
  float* aTSTA = (float*)(ws + A_T_S_TA);
  float* aTSTT = (float*)(ws + A_T_S_TT);
  float* aTDTT = (float*)(ws + A_T_D_TT);
  int* rp_at = (int*)(ws + RP_AT); int* ss_at = (int*)(ws + SS_AT);
  int* rp_ta = (int*)(ws + RP_TA); int* ss_ta = (int*)(ws + SS_TA);
  int* rp_aa = (int*)(ws + RP_AA); int* ss_aa = (int*)(ws + SS_AA);
  int* rp_tt = (int*)(ws + RP_TT); int* ss_tt = (int*)(ws + SS_TT);
  int* cnt = (int*)(ws + CNT);
  int* bsum = (int*)(ws + BSM);
  float* scp = (float*)(ws + SC);
  // layer-2 aliases
  float* za2  = za1;                                  // [NA,64]
  float* zt2  = zt1;                                  // [NT,64]
  float* ota2 = oaa;                                  // [NA,64]
  float* oaa2 = (float*)(ws + OAA + (size_t)NA * OUTF * 4);  // [NA,64]

  const int GA = (NA + 63) / 64, GT = (NT + 63) / 64;
  const int EB1 = (E1 + 255) / 256, EB2 = (E2 + 255) / 256;
  const int NBA = (NA * 8 + 255) / 256, NBT = (NT * 8 + 255) / 256;
  const int NBA1 = (NA + 2047) / 2048, NBT1 = (NT + 2047) / 2048;

  hipMemsetAsync(ws + SC, 0, 256, stream);

  // ---- CSR builds (cnt reused sequentially as histogram, then cursor) ----
  auto build = [&](const int* esrc, const int* edst, int E, int Nd,
                   int* rp, int* ssrc, int nb, int eb) {
    hipMemsetAsync(cnt, 0, (size_t)Nd * 4, stream);
    csr_hist<<<eb, 256, 0, stream>>>(edst, E, cnt);
    scan_blk<<<nb, 256, 0, stream>>>(cnt, rp + 1, bsum, Nd);
    scan_bsum<<<1, 64, 0, stream>>>(bsum, nb);
    scan_add<<<(Nd + 255) / 256, 256, 0, stream>>>(rp, bsum, Nd);
    hipMemcpyAsync(cnt, rp, (size_t)Nd * 4, hipMemcpyDeviceToDevice, stream);
    csr_scatter<<<eb, 256, 0, stream>>>(esrc, edst, E, cnt, ssrc);
  };
  build(eat_s, eat_d, E1, NT, rp_at, ss_at, NBT1, EB1);
  build(eta_s, eta_d, E1, NA, rp_ta, ss_ta, NBA1, EB1);
  build(eaa_s, eaa_d, E2, NA, rp_aa, ss_aa, NBA1, EB2);
  build(ett_s, ett_d, E2, NT, rp_tt, ss_tt, NBT1, EB2);

  // ============ Layer 1 ============
  gemm_k<0><<<dim3(GA,2),256,0,stream>>>(x_a, W_a1, b_a1, nullptr, za1, nullptr, NA, FA, HID);
  gemm_k<0><<<dim3(GT,2),256,0,stream>>>(x_t, W_t1, b_t1, nullptr, zt1, nullptr, NT, FT, HID);
  node_alphas_k<16,4><<<NBA,256,0,stream>>>(za1, NA, as_at1, ad_ta1, as_aa1, ad_aa1,
                                            aASAT, aADTA, aASAA, aADAA);
  node_alphas_k<16,4><<<NBT,256,0,stream>>>(zt1, NT, ad_at1, as_ta1, as_tt1, ad_tt1,
                                            aTDAT, aTSTA, aTSTT, aTDTT);
  agg_k<128><<<(NT+3)/4,256,0,stream>>>(rp_at, ss_at, aASAT, aTDAT, za1, oat, NT);
  agg_k<128><<<(NA+3)/4,256,0,stream>>>(rp_ta, ss_ta, aTSTA, aADTA, zt1, ota, NA);
  agg_k<128><<<(NA+3)/4,256,0,stream>>>(rp_aa, ss_aa, aASAA, aADAA, za1, oaa, NA);
  agg_k<128><<<(NT+3)/4,256,0,stream>>>(rp_tt, ss_tt, aTSTT, aTDTT, zt1, ott, NT);
  // --- semantic scores + combine + LN + relu ---
  gemm_k<1><<<dim3(GA,2),256,0,stream>>>(ota, k1_W, k1_b, q1, nullptr, scp+0, NA, HID, HID);
  gemm_k<1><<<dim3(GA,2),256,0,stream>>>(oaa, k1_W, k1_b, q1, nullptr, scp+1, NA, HID, HID);
  gemm_k<1><<<dim3(GT,2),256,0,stream>>>(oat, k1_W, k1_b, q1, nullptr, scp+2, NT, HID, HID);
  gemm_k<1><<<dim3(GT,2),256,0,stream>>>(ott, k1_W, k1_b, q1, nullptr, scp+3, NT, HID, HID);
  combine_ln_k<128><<<(NA+3)/4,256,0,stream>>>(ota, oaa, scp+0, 1.f/NA, ln1_g, ln1_b, ota, NA); // xa1
  combine_ln_k<128><<<(NT+3)/4,256,0,stream>>>(oat, ott, scp+2, 1.f/NT, ln1_g, ln1_b, oat, NT); // xt1

  // ============ Layer 2 (only the address path feeds the output) ============
  gemm_k<0><<<dim3(GA,1),256,0,stream>>>(ota, W_a2, b_a2, nullptr, za2, nullptr, NA, HID, OUTF);
  gemm_k<0><<<dim3(GT,1),256,0,stream>>>(oat, W_t2, b_t2, nullptr, zt2, nullptr, NT, HID, OUTF);
  node_alphas_k<8,3><<<NBA,256,0,stream>>>(za2, NA, ad_ta2, as_aa2, ad_aa2, ad_aa2,
                                           aADTA, aASAA, aADAA, aADAA);
  node_alphas_k<8,1><<<NBT,256,0,stream>>>(zt2, NT, as_ta2, as_ta2, as_ta2, as_ta2,
                                           aTSTA, aTSTA, aTSTA, aTSTA);
  agg_k<64><<<(NA+3)/4,256,0,stream>>>(rp_ta, ss_ta, aTSTA, aADTA, zt2, ota2, NA);
  agg_k<64><<<(NA+3)/4,256,0,stream>>>(rp_aa, ss_aa, aASAA, aADAA, za2, oaa2, NA);
  // --- scores + combine + LN + relu ---
  gemm_k<1><<<dim3(GA,1),256,0,stream>>>(ota2, k2_W, k2_b, q2, nullptr, scp+4, NA, OUTF, OUTF);
  gemm_k<1><<<dim3(GA,1),256,0,stream>>>(oaa2, k2_W, k2_b, q2, nullptr, scp+5, NA, OUTF, OUTF);
  combine_ln_k<64><<<(NA+3)/4,256,0,stream>>>(ota2, oaa2, scp+4, 1.f/NA, ln2_g, ln2_b, ota2, NA); // xa2

  final_lin_k<<<(NA+3)/4,256,0,stream>>>(ota2, lin_W, lin_b, (float*)d_out, NA);
}

// Round 3
// 909.368 us; speedup vs baseline: 5.9383x; 1.1757x over previous
//
#include <hip/hip_runtime.h>
#include <cstdint>
#include <cstddef>

#define NA 50000
#define NT 100000
#define FA 128
#define FT 64
#define HID 128
#define OUTF 64
#define HEADS 8
#define E1 500000
#define E2 250000
#define NTOT (2*NT + 2*NA)          // concatenated dst-node space
#define ETOT (2*E1 + 2*E2)          // concatenated edge space

typedef __attribute__((ext_vector_type(8))) short short8;
typedef __attribute__((ext_vector_type(4))) float f32x4;

static __device__ __forceinline__ ushort f2b(float f) {  // f32 -> bf16 RNE
  unsigned int u = __float_as_uint(f);
  return (ushort)((u + 0x7fffu + ((u >> 16) & 1u)) >> 16);
}
static __device__ __forceinline__ float b2f(ushort b) {
  return __uint_as_float(((unsigned int)b) << 16);
}

// ============== MFMA bf16 GEMM: C[N,M] = A[N,K]@W[K,M] + bias ==============
// A,W are f32 in memory; converted to bf16 during LDS staging; f32 accumulate.
// MODE 0: store C (f32 or bf16 per OUT_BF16). MODE 1: atomicAdd(sum tanh(C+b)*q).
// Tile 64x64, BK=32, 4 waves (one 16-row strip each). K%32==0, M%64==0.
template<int MODE, int OUT_BF16>
__global__ __launch_bounds__(256) void gemm_mfma(
    const float* __restrict__ A, const float* __restrict__ W,
    const float* __restrict__ bias, const float* __restrict__ qv,
    float* __restrict__ Cf, ushort* __restrict__ Cb,
    float* __restrict__ score, int N, int K, int M)
{
  __shared__ __align__(16) ushort Als[64][32];
  __shared__ __align__(16) ushort Bls[64][32];
  __shared__ float red[4];
  int t = threadIdx.x;
  int row0 = blockIdx.x * 64, col0 = blockIdx.y * 64;
  int w = t >> 6, lane = t & 63;
  int l15 = lane & 15, l4 = lane >> 4;
  f32x4 acc[4] = {{0.f,0.f,0.f,0.f},{0.f,0.f,0.f,0.f},
                  {0.f,0.f,0.f,0.f},{0.f,0.f,0.f,0.f}};
  int arow = t >> 2, akp = (t & 3) << 3;    // A stage: 64 rows x 32 k
  int bcol = t & 63, bkb = t >> 6;          // B stage: 64 cols x 4 k-blocks
  bool aok = (row0 + arow) < N;
  const float* Ap = A + (size_t)(row0 + arow) * K + akp;

  for (int k0 = 0; k0 < K; k0 += 32) {
    union { ushort u[8]; uint4 v; } pa;
    if (aok) {
      float4 a0 = *reinterpret_cast<const float4*>(Ap + k0);
      float4 a1 = *reinterpret_cast<const float4*>(Ap + k0 + 4);
      pa.u[0]=f2b(a0.x); pa.u[1]=f2b(a0.y); pa.u[2]=f2b(a0.z); pa.u[3]=f2b(a0.w);
      pa.u[4]=f2b(a1.x); pa.u[5]=f2b(a1.y); pa.u[6]=f2b(a1.z); pa.u[7]=f2b(a1.w);
    } else {
      pa.v = make_uint4(0,0,0,0);
    }
    *reinterpret_cast<uint4*>(&Als[arow][akp]) = pa.v;
    union { ushort u[8]; uint4 v; } pb;
#pragma unroll
    for (int j = 0; j < 8; j++)
      pb.u[j] = f2b(W[(size_t)(k0 + bkb*8 + j) * M + col0 + bcol]);
    // XOR-swizzle k-block by (col&3): breaks the 32-lanes-per-4-banks pattern
    *reinterpret_cast<uint4*>(&Bls[bcol][(bkb ^ (bcol & 3)) * 8]) = pb.v;
    __syncthreads();
    short8 af = *reinterpret_cast<const short8*>(&Als[16*w + l15][l4 * 8]);
#pragma unroll
    for (int n = 0; n < 4; n++) {
      int bc = 16*n + l15;
      short8 bf = *reinterpret_cast<const short8*>(&Bls[bc][(l4 ^ (bc & 3)) * 8]);
      acc[n] = __builtin_amdgcn_mfma_f32_16x16x32_bf16(af, bf, acc[n], 0, 0, 0);
    }
    __syncthreads();
  }

  if (MODE == 0) {
#pragma unroll
    for (int n = 0; n < 4; n++) {
      int col = col0 + 16*n + l15;
      float bv = bias[col];
#pragma unroll
      for (int r = 0; r < 4; r++) {
        int row = row0 + 16*w + l4*4 + r;
        if (row < N) {
          float v = acc[n][r] + bv;
          if (OUT_BF16) Cb[(size_t)row * M + col] = f2b(v);
          else          Cf[(size_t)row * M + col] = v;
        }
      }
    }
  } else {
    float local = 0.f;
#pragma unroll
    for (int n = 0; n < 4; n++) {
      int col = col0 + 16*n + l15;
      float bv = bias[col], qq = qv[col];
#pragma unroll
      for (int r = 0; r < 4; r++) {
        int row = row0 + 16*w + l4*4 + r;
        if (row < N) local += tanhf(acc[n][r] + bv) * qq;
      }
    }
#pragma unroll
    for (int o = 32; o > 0; o >>= 1) local += __shfl_xor(local, o);
    if (lane == 0) red[w] = local;
    __syncthreads();
    if (t == 0) atomicAdd(score, red[0] + red[1] + red[2] + red[3]);
  }
}

// --------- per-node attention logits from bf16 z: o_k[n,h]=dot(z,v_k) ------
template<int D, int NV>
__global__ void node_alphas_k(const ushort* __restrict__ z, int N,
    const float* __restrict__ v0, const float* __restrict__ v1,
    const float* __restrict__ v2, const float* __restrict__ v3,
    float* __restrict__ o0, float* __restrict__ o1,
    float* __restrict__ o2, float* __restrict__ o3)
{
  int t = blockIdx.x * blockDim.x + threadIdx.x;
  if (t >= N * HEADS) return;
  int h = t & 7;
  const ushort* zp = z + (size_t)(t >> 3) * (HEADS * D) + h * D;
  float s0 = 0.f, s1 = 0.f, s2 = 0.f, s3 = 0.f;
#pragma unroll
  for (int i = 0; i < D; i++) {
    float zv = b2f(zp[i]);
    s0 = fmaf(zv, v0[h * D + i], s0);
    if (NV > 1) s1 = fmaf(zv, v1[h * D + i], s1);
    if (NV > 2) s2 = fmaf(zv, v2[h * D + i], s2);
    if (NV > 3) s3 = fmaf(zv, v3[h * D + i], s3);
  }
  o0[t] = s0;
  if (NV > 1) o1[t] = s1;
  if (NV > 2) o2[t] = s2;
  if (NV > 3) o3[t] = s3;
}

// ============== fused CSR build over 4 concatenated edge types =============
__global__ void csr_hist4(const int* __restrict__ d0, const int* __restrict__ d1,
    const int* __restrict__ d2, const int* __restrict__ d3, int* __restrict__ cnt)
{
  int e = blockIdx.x * 256 + threadIdx.x;
  int d;
  if      (e < E1)          d = d0[e];
  else if (e < 2*E1)        d = d1[e - E1] + NT;
  else if (e < 2*E1 + E2)   d = d2[e - 2*E1] + NT + NA;
  else if (e < ETOT)        d = d3[e - 2*E1 - E2] + NT + NA + NA;
  else return;
  atomicAdd(&cnt[d], 1);
}

__global__ void csr_scatter4(const int* __restrict__ s0, const int* __restrict__ d0,
    const int* __restrict__ s1, const int* __restrict__ d1,
    const int* __restrict__ s2, const int* __restrict__ d2,
    const int* __restrict__ s3, const int* __restrict__ d3,
    int* __restrict__ cursor, int* __restrict__ ssrc)
{
  int e = blockIdx.x * 256 + threadIdx.x;
  int d, s;
  if      (e < E1)          { d = d0[e];                          s = s0[e]; }
  else if (e < 2*E1)        { d = d1[e - E1] + NT;                s = s1[e - E1]; }
  else if (e < 2*E1 + E2)   { d = d2[e - 2*E1] + NT + NA;        s = s2[e - 2*E1]; }
  else if (e < ETOT)        { d = d3[e - 2*E1 - E2] + NT + NA + NA; s = s3[e - 2*E1 - E2]; }
  else return;
  int p = atomicAdd(&cursor[d], 1);
  ssrc[p] = s;
}

// per-block inclusive scan (256 thr x 8) of in -> rp1 (=rp+1); totals -> bsum
__global__ __launch_bounds__(256) void scan_blk(const int* __restrict__ in,
    int* __restrict__ rp1, int* __restrict__ bsum, int n)
{
  __shared__ int sh[256];
  int base = blockIdx.x * 2048;
  int t = threadIdx.x;
  int v[8]; int s = 0;
#pragma unroll
  for (int k = 0; k < 8; k++) {
    int i = base + t * 8 + k;
    v[k] = (i < n) ? in[i] : 0; s += v[k];
  }
  sh[t] = s; __syncthreads();
  for (int o = 1; o < 256; o <<= 1) {
    int x = (t >= o) ? sh[t - o] : 0;
    __syncthreads(); sh[t] += x; __syncthreads();
  }
  int run = (t == 0) ? 0 : sh[t - 1];
  if (t == 255 && bsum) bsum[blockIdx.x] = sh[255];
#pragma unroll
  for (int k = 0; k < 8; k++) {
    int i = base + t * 8 + k;
    run += v[k];
    if (i < n) rp1[i] = run;
  }
}

// exclusive scan of up to 256 block sums in-place
__global__ void scan_bsum(int* __restrict__ bsum, int nb)
{
  __shared__ int sh[256];
  int t = threadIdx.x;
  int v = (t < nb) ? bsum[t] : 0;
  sh[t] = v; __syncthreads();
  for (int o = 1; o < 256; o <<= 1) {
    int x = (t >= o) ? sh[t - o] : 0;
    __syncthreads(); sh[t] += x; __syncthreads();
  }
  if (t < nb) bsum[t] = sh[t] - v;
}

__global__ void scan_add(int* __restrict__ rp, const int* __restrict__ bsum, int n)
{
  int i = blockIdx.x * blockDim.x + threadIdx.x;
  if (i == 0) rp[0] = 0;
  if (i < n) rp[i + 1] += bsum[i >> 11];
}

// =============== atomic-free GAT aggregation: one wave per dst node ========
// z is bf16. softmax: lane = h*8+j (8 edges x 8 heads); accumulate: all lanes
// walk edges together (wave-uniform src), gather 2 (F=128) or 1 (F=64) feats.
template<int F>
__global__ __launch_bounds__(256) void agg_k(const int* __restrict__ rp,
    const int* __restrict__ ssrc,
    const float* __restrict__ als, const float* __restrict__ ald,
    const ushort* __restrict__ z, float* __restrict__ out, int Nd)
{
  int wv = threadIdx.x >> 6, lane = threadIdx.x & 63;
  int n = blockIdx.x * 4 + wv;
  if (n >= Nd) return;
  int start = rp[n], end = rp[n + 1];
  int h = lane >> 3, j = lane & 7;
  float ad_h = ald[(size_t)n * 8 + h];

  float m = -1e30f;
  for (int e0 = start; e0 < end; e0 += 8) {
    int e = e0 + j;
    float a = -1e30f;
    if (e < end) {
      int s = ssrc[e];
      a = als[(size_t)s * 8 + h] + ad_h;
      a = a > 0.f ? a : 0.2f * a;
    }
    m = fmaxf(m, a);
  }
  m = fmaxf(m, __shfl_xor(m, 1));
  m = fmaxf(m, __shfl_xor(m, 2));
  m = fmaxf(m, __shfl_xor(m, 4));

  float den = 0.f;
  for (int e0 = start; e0 < end; e0 += 8) {
    int e = e0 + j;
    if (e < end) {
      int s = ssrc[e];
      float a = als[(size_t)s * 8 + h] + ad_h;
      a = a > 0.f ? a : 0.2f * a;
      den += __expf(a - m);
    }
  }
  den += __shfl_xor(den, 1);
  den += __shfl_xor(den, 2);
  den += __shfl_xor(den, 4);
  float inv = 1.f / fmaxf(den, 1e-16f);

  if (F == 128) {
    float accx = 0.f, accy = 0.f;
    for (int e = start; e < end; e++) {
      int s = ssrc[e];
      float a = als[(size_t)s * 8 + h] + ad_h;
      a = a > 0.f ? a : 0.2f * a;
      float wgt = __expf(a - m) * inv;
      unsigned int zv = *reinterpret_cast<const unsigned int*>(z + (size_t)s * 128 + lane * 2);
      accx = fmaf(wgt, __uint_as_float(zv << 16), accx);
      accy = fmaf(wgt, __uint_as_float(zv & 0xffff0000u), accy);
    }
    float2 st; st.x = fmaxf(accx, 0.f); st.y = fmaxf(accy, 0.f);
    *reinterpret_cast<float2*>(out + (size_t)n * 128 + lane * 2) = st;
  } else {
    float acc = 0.f;
    for (int e = start; e < end; e++) {
      int s = ssrc[e];
      float a = als[(size_t)s * 8 + h] + ad_h;
      a = a > 0.f ? a : 0.2f * a;
      float wgt = __expf(a - m) * inv;
      acc = fmaf(wgt, b2f(z[(size_t)s * 64 + lane]), acc);
    }
    out[(size_t)n * 64 + lane] = fmaxf(acc, 0.f);
  }
}

// ---- semantic softmax (K=2) combine + LayerNorm + ReLU, wave per node ----
template<int F>
__global__ __launch_bounds__(256) void combine_ln_k(
    const float* __restrict__ o0, const float* __restrict__ o1,
    const float* __restrict__ sc, float inv_n,
    const float* __restrict__ g, const float* __restrict__ b,
    float* __restrict__ outp, int N)
{
  int wv = threadIdx.x >> 6, lane = threadIdx.x & 63;
  int n = blockIdx.x * 4 + wv;
  if (n >= N) return;
  float s0 = sc[0] * inv_n, s1 = sc[1] * inv_n;
  float mx = fmaxf(s0, s1);
  float e0 = __expf(s0 - mx), e1 = __expf(s1 - mx);
  float w0 = e0 / (e0 + e1), w1 = e1 / (e0 + e1);
  constexpr int J = F / 64;
  float x[J];
#pragma unroll
  for (int j = 0; j < J; j++) {
    int idx = lane + 64 * j;
    x[j] = w0 * o0[(size_t)n * F + idx] + w1 * o1[(size_t)n * F + idx];
  }
  float sum = 0.f;
#pragma unroll
  for (int j = 0; j < J; j++) sum += x[j];
#pragma unroll
  for (int o = 32; o > 0; o >>= 1) sum += __shfl_xor(sum, o);
  float mu = sum / F;
  float vs = 0.f;
#pragma unroll
  for (int j = 0; j < J; j++) { float dd = x[j] - mu; vs = fmaf(dd, dd, vs); }
#pragma unroll
  for (int o = 32; o > 0; o >>= 1) vs += __shfl_xor(vs, o);
  float rstd = rsqrtf(vs / F + 1e-5f);
#pragma unroll
  for (int j = 0; j < J; j++) {
    int idx = lane + 64 * j;
    float y = (x[j] - mu) * rstd * g[idx] + b[idx];
    outp[(size_t)n * F + idx] = fmaxf(y, 0.f);
  }
}

// ---- final linear [N,64] @ [64,2] + b, wave per node ----
__global__ __launch_bounds__(256) void final_lin_k(const float* __restrict__ xa,
    const float* __restrict__ W, const float* __restrict__ bias,
    float* __restrict__ outp, int N)
{
  int wv = threadIdx.x >> 6, lane = threadIdx.x & 63;
  int n = blockIdx.x * 4 + wv;
  if (n >= N) return;
  float v = xa[(size_t)n * 64 + lane];
  float p0 = v * W[lane * 2 + 0];
  float p1 = v * W[lane * 2 + 1];
#pragma unroll
  for (int o = 32; o > 0; o >>= 1) { p0 += __shfl_xor(p0, o); p1 += __shfl_xor(p1, o); }
  if (lane == 0) {
    outp[(size_t)n * 2 + 0] = p0 + bias[0];
    outp[(size_t)n * 2 + 1] = p1 + bias[1];
  }
}

extern "C" void kernel_launch(void* const* d_in, const int* in_sizes, int n_in,
                              void* d_out, int out_size, void* d_ws, size_t ws_size,
                              hipStream_t stream)
{
  (void)in_sizes; (void)n_in; (void)out_size;
  const float* x_a   = (const float*)d_in[0];
  const float* x_t   = (const float*)d_in[1];
  const int* eat_s = (const int*)d_in[2];
  const int* eat_d = (const int*)d_in[3];
  const int* eta_s = (const int*)d_in[4];
  const int* eta_d = (const int*)d_in[5];
  const int* eaa_s = (const int*)d_in[6];
  const int* eaa_d = (const int*)d_in[7];
  const int* ett_s = (const int*)d_in[8];
  const int* ett_d = (const int*)d_in[9];
  const float* W_a1 = (const float*)d_in[10]; const float* b_a1 = (const float*)d_in[11];
  const float* W_t1 = (const float*)d_in[12]; const float* b_t1 = (const float*)d_in[13];
  const float* as_at1 = (const float*)d_in[14]; const float* ad_at1 = (const float*)d_in[15];
  const float* as_ta1 = (const float*)d_in[16]; const float* ad_ta1 = (const float*)d_in[17];
  const float* as_aa1 = (const float*)d_in[18]; const float* ad_aa1 = (const float*)d_in[19];
  const float* as_tt1 = (const float*)d_in[20]; const float* ad_tt1 = (const float*)d_in[21];
  const float* k1_W = (const float*)d_in[22]; const float* k1_b = (const float*)d_in[23];
  const float* q1   = (const float*)d_in[24];
  const float* W_a2 = (const float*)d_in[25]; const float* b_a2 = (const float*)d_in[26];
  const float* W_t2 = (const float*)d_in[27]; const float* b_t2 = (const float*)d_in[28];
  const float* as_ta2 = (const float*)d_in[31]; const float* ad_ta2 = (const float*)d_in[32];
  const float* as_aa2 = (const float*)d_in[33]; const float* ad_aa2 = (const float*)d_in[34];
  const float* k2_W = (const float*)d_in[37]; const float* k2_b = (const float*)d_in[38];
  const float* q2   = (const float*)d_in[39];
  const float* ln1_g = (const float*)d_in[40]; const float* ln1_b = (const float*)d_in[41];
  const float* ln2_g = (const float*)d_in[42]; const float* ln2_b = (const float*)d_in[43];
  const float* lin_W = (const float*)d_in[44]; const float* lin_b = (const float*)d_in[45];

  char* ws = (char*)d_ws;
  size_t off = 0;
  auto alloc = [&](size_t bytes) {
    size_t o = off; off += (bytes + 255) & ~(size_t)255; return o;
  };
  size_t ZA1 = alloc((size_t)NA * HID * 2);     // bf16 z_a; layer2 za2 aliases
  size_t ZT1 = alloc((size_t)NT * HID * 2);     // bf16 z_t; layer2 zt2 aliases
  size_t OTA = alloc((size_t)NA * HID * 4);     // f32 -> xa1 in-place
  size_t OAA = alloc((size_t)NA * HID * 4);     // f32; layer2 o_ta2|o_aa2 alias
  size_t OAT = alloc((size_t)NT * HID * 4);     // f32 -> xt1 in-place
  size_t OTT = alloc((size_t)NT * HID * 4);
  size_t A_AS_AT = alloc((size_t)NA * 8 * 4);
  size_t A_AD_TA = alloc((size_t)NA * 8 * 4);
  size_t A_AS_AA = alloc((size_t)NA * 8 * 4);
  size_t A_AD_AA = alloc((size_t)NA * 8 * 4);
  size_t A_T_D_AT = alloc((size_t)NT * 8 * 4);
  size_t A_T_S_TA = alloc((size_t)NT * 8 * 4);
  size_t A_T_S_TT = alloc((size_t)NT * 8 * 4);
  size_t A_T_D_TT = alloc((size_t)NT * 8 * 4);
  // fused CSR: node order [at:NT][ta:NA][aa:NA][tt:NT]; edges concatenated
  size_t RP  = alloc((size_t)(NTOT + 1) * 4);
  size_t SS  = alloc((size_t)ETOT * 4);
  size_t CNT = alloc((size_t)NTOT * 4);
  size_t BSM = alloc(256 * 4);
  size_t SC  = alloc(256);                      // 6 score accumulators
  if (off > ws_size) return;                    // fail visibly

  ushort* za1 = (ushort*)(ws + ZA1);
  ushort* zt1 = (ushort*)(ws + ZT1);
  float* ota = (float*)(ws + OTA);
  float* oaa = (float*)(ws + OAA);
  float* oat = (float*)(ws + OAT);
  float* ott = (float*)(ws + OTT);
  float* aASAT = (float*)(ws + A_AS_AT);
  float* aADTA = (float*)(ws + A_AD_TA);
  float* aASAA = (float*)(ws + A_AS_AA);
  float* aADAA = (float*)(ws + A_AD_AA);
  float* aTDAT = (float*)(ws + A_T_D_AT);
  float* aTSTA = (float*)(ws + A_T_S_TA);
  float* aTSTT = (float*)(ws + A_T_S_TT);
  float* aTDTT = (float*)(ws + A_T_D_TT);
  int* rp   = (int*)(ws + RP);
  int* ssrc = (int*)(ws + SS);
  int* cnt  = (int*)(ws + CNT);
  int* bsum = (int*)(ws + BSM);
  float* scp = (float*)(ws + SC);
  // per-type CSR views (global positions; ssrc shared)
  int* rp_at = rp;                 // NT nodes
  int* rp_ta = rp + NT;            // NA nodes
  int* rp_aa = rp + NT + NA;       // NA nodes
  int* rp_tt = rp + NT + 2*NA;     // NT nodes
  // layer-2 aliases
  ushort* za2 = za1;                                  // [NA,64] bf16
  ushort* zt2 = zt1;                                  // [NT,64] bf16
  float* ota2 = oaa;                                  // [NA,64] f32
  float* oaa2 = (float*)(ws + OAA + (size_t)NA * OUTF * 4);  // [NA,64] f32

  const int GA = (NA + 63) / 64, GT = (NT + 63) / 64;
  const int NBA = (NA * 8 + 255) / 256, NBT = (NT * 8 + 255) / 256;
  const int EBL = (ETOT + 255) / 256;
  const int SBL = (NTOT + 2047) / 2048;   // 147 scan blocks

  hipMemsetAsync(ws + SC, 0, 256, stream);

  // ---- fused CSR build (one counting sort over all 4 edge types) ----
  hipMemsetAsync(cnt, 0, (size_t)NTOT * 4, stream);
  csr_hist4<<<EBL, 256, 0, stream>>>(eat_d, eta_d, eaa_d, ett_d, cnt);
  scan_blk<<<SBL, 256, 0, stream>>>(cnt, rp + 1, bsum, NTOT);
  scan_bsum<<<1, 256, 0, stream>>>(bsum, SBL);
  scan_add<<<(NTOT + 255) / 256, 256, 0, stream>>>(rp, bsum, NTOT);
  hipMemcpyAsync(cnt, rp, (size_t)NTOT * 4, hipMemcpyDeviceToDevice, stream);
  csr_scatter4<<<EBL, 256, 0, stream>>>(eat_s, eat_d, eta_s, eta_d,
                                        eaa_s, eaa_d, ett_s, ett_d, cnt, ssrc);

  // ============ Layer 1 ============
  gemm_mfma<0,1><<<dim3(GA,2),256,0,stream>>>(x_a, W_a1, b_a1, nullptr, nullptr, za1, nullptr, NA, FA, HID);
  gemm_mfma<0,1><<<dim3(GT,2),256,0,stream>>>(x_t, W_t1, b_t1, nullptr, nullptr, zt1, nullptr, NT, FT, HID);
  node_alphas_k<16,4><<<NBA,256,0,stream>>>(za1, NA, as_at1, ad_ta1, as_aa1, ad_aa1,
                                            aASAT, aADTA, aASAA, aADAA);
  node_alphas_k<16,4><<<NBT,256,0,stream>>>(zt1, NT, ad_at1, as_ta1, as_tt1, ad_tt1,
                                            aTDAT, aTSTA, aTSTT, aTDTT);
  agg_k<128><<<(NT+3)/4,256,0,stream>>>(rp_at, ssrc, aASAT, aTDAT, za1, oat, NT);
  agg_k<128><<<(NA+3)/4,256,0,stream>>>(rp_ta, ssrc, aTSTA, aADTA, zt1, ota, NA);
  agg_k<128><<<(NA+3)/4,256,0,stream>>>(rp_aa, ssrc, aASAA, aADAA, za1, oaa, NA);
  agg_k<128><<<(NT+3)/4,256,0,stream>>>(rp_tt, ssrc, aTSTT, aTDTT, zt1, ott, NT);
  // --- semantic scores + combine + LN + relu ---
  gemm_mfma<1,0><<<dim3(GA,2),256,0,stream>>>(ota, k1_W, k1_b, q1, nullptr, nullptr, scp+0, NA, HID, HID);
  gemm_mfma<1,0><<<dim3(GA,2),256,0,stream>>>(oaa, k1_W, k1_b, q1, nullptr, nullptr, scp+1, NA, HID, HID);
  gemm_mfma<1,0><<<dim3(GT,2),256,0,stream>>>(oat, k1_W, k1_b, q1, nullptr, nullptr, scp+2, NT, HID, HID);
  gemm_mfma<1,0><<<dim3(GT,2),256,0,stream>>>(ott, k1_W, k1_b, q1, nullptr, nullptr, scp+3, NT, HID, HID);
  combine_ln_k<128><<<(NA+3)/4,256,0,stream>>>(ota, oaa, scp+0, 1.f/NA, ln1_g, ln1_b, ota, NA); // xa1
  combine_ln_k<128><<<(NT+3)/4,256,0,stream>>>(oat, ott, scp+2, 1.f/NT, ln1_g, ln1_b, oat, NT); // xt1

  // ============ Layer 2 (only the address path feeds the output) ============
  gemm_mfma<0,1><<<dim3(GA,1),256,0,stream>>>(ota, W_a2, b_a2, nullptr, nullptr, za2, nullptr, NA, HID, OUTF);
  gemm_mfma<0,1><<<dim3(GT,1),256,0,stream>>>(oat, W_t2, b_t2, nullptr, nullptr, zt2, nullptr, NT, HID, OUTF);
  node_alphas_k<8,3><<<NBA,256,0,stream>>>(za2, NA, ad_ta2, as_aa2, ad_aa2, ad_aa2,
                                           aADTA, aASAA, aADAA, aADAA);
  node_alphas_k<8,1><<<NBT,256,0,stream>>>(zt2, NT, as_ta2, as_ta2, as_ta2, as_ta2,
                                           aTSTA, aTSTA, aTSTA, aTSTA);
  agg_k<64><<<(NA+3)/4,256,0,stream>>>(rp_ta, ssrc, aTSTA, aADTA, zt2, ota2, NA);
  agg_k<64><<<(NA+3)/4,256,0,stream>>>(rp_aa, ssrc, aASAA, aADAA, za2, oaa2, NA);
  // --- scores + combine + LN + relu ---
  gemm_mfma<1,0><<<dim3(GA,1),256,0,stream>>>(ota2, k2_W, k2_b, q2, nullptr, nullptr, scp+4, NA, OUTF, OUTF);
  gemm_mfma<1,0><<<dim3(GA,1),256,0,stream>>>(oaa2, k2_W, k2_b, q2, nullptr, nullptr, scp+5, NA, OUTF, OUTF);
  combine_ln_k<64><<<(NA+3)/4,256,0,stream>>>(ota2, oaa2, scp+4, 1.f/NA, ln2_g, ln2_b, ota2, NA); // xa2

  final_lin_k<<<(NA+3)/4,256,0,stream>>>(ota2, lin_W, lin_b, (float*)d_out, NA);
}